// Round 10
// baseline (532.199 us; speedup 1.0000x reference)
//
#include <hip/hip_runtime.h>

#define NN 40000
#define NE 640000
#define DH 128
#define DO 17
#define SLOTS 64

typedef __attribute__((ext_vector_type(8))) short short8v;
typedef __attribute__((ext_vector_type(4))) float f32x4;

__device__ inline float b2f(unsigned short u) {
  union { unsigned int i; float f; } c;
  c.i = (unsigned int)u << 16;
  return c.f;
}
__device__ inline unsigned short f2b(float f) {
  union { float f; unsigned int i; } c;
  c.f = f;
  unsigned int r = c.i + 0x7fff + ((c.i >> 16) & 1);  // RNE
  return (unsigned short)(r >> 16);
}

// ---------------- CSR build ----------------

__global__ void k_fill(const int* __restrict__ src, const int* __restrict__ dst,
                       int* __restrict__ cursor, unsigned short* __restrict__ csr) {
  int e = blockIdx.x * blockDim.x + threadIdx.x;
  if (e >= NE) return;
  int d = dst[e];
  int pos = atomicAdd(&cursor[d], 1);
  if (pos < SLOTS) csr[(d << 6) + pos] = (unsigned short)src[e];
}

// ---------------- x -> hi/lo bf16 planes ----------------

__global__ __launch_bounds__(256) void k_tobf16(const float* __restrict__ x,
                                                unsigned short* __restrict__ hi,
                                                unsigned short* __restrict__ lo) {
  int t = blockIdx.x * 256 + threadIdx.x;
  if (t >= NN * 32) return;
  float4 v = *(const float4*)(x + (size_t)t * 4);
  ushort4 h, l;
  h.x = f2b(v.x); l.x = f2b(v.x - b2f(h.x));
  h.y = f2b(v.y); l.y = f2b(v.y - b2f(h.y));
  h.z = f2b(v.z); l.z = f2b(v.z - b2f(h.z));
  h.w = f2b(v.w); l.w = f2b(v.w - b2f(h.w));
  *(ushort4*)(hi + (size_t)t * 4) = h;
  *(ushort4*)(lo + (size_t)t * 4) = l;
}

// ---------------- weight transpose + split: WT[n][k], k in [Wl;Wr] ----------------

__global__ __launch_bounds__(256) void k_splitw(const float* __restrict__ Wl,
                                                const float* __restrict__ Wr,
                                                unsigned short* __restrict__ Thi,
                                                unsigned short* __restrict__ Tlo) {
  int n = blockIdx.x;   // 0..127
  int k = threadIdx.x;  // 0..255
  float v = (k < 128) ? Wl[(size_t)k * 128 + n] : Wr[(size_t)(k - 128) * 128 + n];
  unsigned short hi = f2b(v);
  unsigned short lo = f2b(v - b2f(hi));
  Thi[(size_t)n * 256 + k] = hi;
  Tlo[(size_t)n * 256 + k] = lo;
}

// ---------------- fused layer: mean-gather + split-bf16 MFMA GEMM ----------------
// BM=32, BN=128, 4 waves, 1250 blocks. Phase 1: block's 32 node-means -> LDS
// (hi/lo). Phase 2: h' = relu([mean|h] @ WT^T + b) -> ping-pong planes.
// In/out planes are distinct buffers (gather reads neighbors => no in-place).

__global__ __launch_bounds__(256) void k_layer(
    const unsigned short* __restrict__ HhiIn,
    const unsigned short* __restrict__ HloIn,
    const unsigned short* __restrict__ WThi,
    const unsigned short* __restrict__ WTlo,
    const float* __restrict__ bias,
    const int* __restrict__ cursor,
    const unsigned short* __restrict__ csr,
    unsigned short* __restrict__ Ohi,
    unsigned short* __restrict__ Olo) {
  __shared__ unsigned short Mh[32][136];  // mean hi, 272B rows
  __shared__ unsigned short Ml[32][136];
  __shared__ unsigned short Ah[32][40];
  __shared__ unsigned short Al[32][40];
  __shared__ unsigned short Bh[128][40];
  __shared__ unsigned short Bl[128][40];
  const int tid = threadIdx.x;
  const int row0 = blockIdx.x * 32;
  const int w = tid >> 6;
  const int lane = tid & 63;
  const int li = lane & 15;
  const int lg = lane >> 4;

  // ---- phase 1: gather means for 32 nodes (wave = 2 nodes, 8B/lane) ----
  {
    const int half = lane >> 5;
    const int ch4 = lane & 31;
    const ushort4* in4 = (const ushort4*)HhiIn;
#pragma unroll
    for (int p = 0; p < 4; ++p) {
      int nl = p * 8 + w * 2 + half;
      int node = row0 + nl;
      int deg = cursor[node];
      int cnt = deg > SLOTS ? SLOTS : deg;
      const unsigned short* idx = csr + ((size_t)node << 6);
      float ax = 0.f, ay = 0.f, az = 0.f, aw = 0.f;
#define GATH(S, COND)                                    \
      if (COND) {                                        \
        ushort4 v = in4[(size_t)(S)*32 + ch4];           \
        ax += b2f(v.x); ay += b2f(v.y);                  \
        az += b2f(v.z); aw += b2f(v.w);                  \
      }
      for (int b = 0; b < cnt; b += 8) {
        ushort4 i0 = *(const ushort4*)(idx + b);
        ushort4 i1 = *(const ushort4*)(idx + b + 4);
        GATH(i0.x, true)
        GATH(i0.y, b + 1 < cnt)
        GATH(i0.z, b + 2 < cnt)
        GATH(i0.w, b + 3 < cnt)
        GATH(i1.x, b + 4 < cnt)
        GATH(i1.y, b + 5 < cnt)
        GATH(i1.z, b + 6 < cnt)
        GATH(i1.w, b + 7 < cnt)
      }
#undef GATH
      float inv = 1.0f / (float)(deg > 0 ? deg : 1);
      ax *= inv; ay *= inv; az *= inv; aw *= inv;
      ushort4 h, l;
      h.x = f2b(ax); l.x = f2b(ax - b2f(h.x));
      h.y = f2b(ay); l.y = f2b(ay - b2f(h.y));
      h.z = f2b(az); l.z = f2b(az - b2f(h.z));
      h.w = f2b(aw); l.w = f2b(aw - b2f(h.w));
      *(ushort4*)&Mh[nl][ch4 * 4] = h;
      *(ushort4*)&Ml[nl][ch4 * 4] = l;
    }
  }

  // ---- phase 2: MFMA GEMM ----
  f32x4 acc00 = {0.f, 0.f, 0.f, 0.f};
  f32x4 acc01 = acc00, acc10 = acc00, acc11 = acc00;

  const int ar = tid >> 3, af = tid & 7;
  const int bc = tid >> 1, bs = (tid & 1) * 16;

  for (int kc = 0; kc < 8; ++kc) {
    ushort4 a_hi, a_lo;
    if (kc >= 4) {
      size_t off = (size_t)(row0 + ar) * 128 + (kc - 4) * 32 + af * 4;
      a_hi = *(const ushort4*)(HhiIn + off);
      a_lo = *(const ushort4*)(HloIn + off);
    }
    size_t woff = (size_t)bc * 256 + kc * 32 + bs;
    uint4 b_h0 = *(const uint4*)(WThi + woff);
    uint4 b_h1 = *(const uint4*)(WThi + woff + 8);
    uint4 b_l0 = *(const uint4*)(WTlo + woff);
    uint4 b_l1 = *(const uint4*)(WTlo + woff + 8);
    __syncthreads();
    if (kc >= 4) {
      *(ushort4*)&Ah[ar][af * 4] = a_hi;
      *(ushort4*)&Al[ar][af * 4] = a_lo;
    }
    *(uint4*)&Bh[bc][bs] = b_h0;
    *(uint4*)&Bh[bc][bs + 8] = b_h1;
    *(uint4*)&Bl[bc][bs] = b_l0;
    *(uint4*)&Bl[bc][bs + 8] = b_l1;
    __syncthreads();
    short8v a0h, a1h, a0l, a1l;
    if (kc < 4) {
      a0h = *(const short8v*)&Mh[li][kc * 32 + lg * 8];
      a1h = *(const short8v*)&Mh[16 + li][kc * 32 + lg * 8];
      a0l = *(const short8v*)&Ml[li][kc * 32 + lg * 8];
      a1l = *(const short8v*)&Ml[16 + li][kc * 32 + lg * 8];
    } else {
      a0h = *(const short8v*)&Ah[li][lg * 8];
      a1h = *(const short8v*)&Ah[16 + li][lg * 8];
      a0l = *(const short8v*)&Al[li][lg * 8];
      a1l = *(const short8v*)&Al[16 + li][lg * 8];
    }
    short8v b0h = *(const short8v*)&Bh[w * 32 + li][lg * 8];
    short8v b1h = *(const short8v*)&Bh[w * 32 + 16 + li][lg * 8];
    short8v b0l = *(const short8v*)&Bl[w * 32 + li][lg * 8];
    short8v b1l = *(const short8v*)&Bl[w * 32 + 16 + li][lg * 8];
    acc00 = __builtin_amdgcn_mfma_f32_16x16x32_bf16(a0h, b0h, acc00, 0, 0, 0);
    acc00 = __builtin_amdgcn_mfma_f32_16x16x32_bf16(a0l, b0h, acc00, 0, 0, 0);
    acc00 = __builtin_amdgcn_mfma_f32_16x16x32_bf16(a0h, b0l, acc00, 0, 0, 0);
    acc01 = __builtin_amdgcn_mfma_f32_16x16x32_bf16(a0h, b1h, acc01, 0, 0, 0);
    acc01 = __builtin_amdgcn_mfma_f32_16x16x32_bf16(a0l, b1h, acc01, 0, 0, 0);
    acc01 = __builtin_amdgcn_mfma_f32_16x16x32_bf16(a0h, b1l, acc01, 0, 0, 0);
    acc10 = __builtin_amdgcn_mfma_f32_16x16x32_bf16(a1h, b0h, acc10, 0, 0, 0);
    acc10 = __builtin_amdgcn_mfma_f32_16x16x32_bf16(a1l, b0h, acc10, 0, 0, 0);
    acc10 = __builtin_amdgcn_mfma_f32_16x16x32_bf16(a1h, b0l, acc10, 0, 0, 0);
    acc11 = __builtin_amdgcn_mfma_f32_16x16x32_bf16(a1h, b1h, acc11, 0, 0, 0);
    acc11 = __builtin_amdgcn_mfma_f32_16x16x32_bf16(a1l, b1h, acc11, 0, 0, 0);
    acc11 = __builtin_amdgcn_mfma_f32_16x16x32_bf16(a1h, b1l, acc11, 0, 0, 0);
  }

  // epilogue: C/D layout col=lane&15, row=(lane>>4)*4+reg
  const int c0 = w * 32 + li;
  const float bv0 = bias[c0];
  const float bv1 = bias[c0 + 16];
#pragma unroll
  for (int reg = 0; reg < 4; ++reg) {
    int r0 = row0 + lg * 4 + reg;
    int r1 = r0 + 16;
    float v;
    unsigned short h;
    v = acc00[reg] + bv0; v = v > 0.f ? v : 0.f;
    h = f2b(v); Ohi[(size_t)r0 * 128 + c0] = h; Olo[(size_t)r0 * 128 + c0] = f2b(v - b2f(h));
    v = acc01[reg] + bv1; v = v > 0.f ? v : 0.f;
    h = f2b(v); Ohi[(size_t)r0 * 128 + c0 + 16] = h; Olo[(size_t)r0 * 128 + c0 + 16] = f2b(v - b2f(h));
    v = acc10[reg] + bv0; v = v > 0.f ? v : 0.f;
    h = f2b(v); Ohi[(size_t)r1 * 128 + c0] = h; Olo[(size_t)r1 * 128 + c0] = f2b(v - b2f(h));
    v = acc11[reg] + bv1; v = v > 0.f ? v : 0.f;
    h = f2b(v); Ohi[(size_t)r1 * 128 + c0 + 16] = h; Olo[(size_t)r1 * 128 + c0 + 16] = f2b(v - b2f(h));
  }
}

// ---------------- layer-4 projection from hi/lo planes ----------------

__global__ __launch_bounds__(256) void k_lastproj(const unsigned short* __restrict__ Hhi,
                                                  const unsigned short* __restrict__ Hlo,
                                                  const float* __restrict__ Wl,
                                                  const float* __restrict__ Wr,
                                                  const float* __restrict__ bias,
                                                  float* __restrict__ U,
                                                  float* __restrict__ V) {
  __shared__ float As[64][132];
  const int t = threadIdx.x;
  const int row0 = blockIdx.x * 64;

#pragma unroll
  for (int i = 0; i < 8; ++i) {
    int idx = i * 256 + t;
    int r = idx >> 5, c4 = idx & 31;
    size_t off = (size_t)(row0 + r) * 128 + c4 * 4;
    ushort4 h = *(const ushort4*)(Hhi + off);
    ushort4 l = *(const ushort4*)(Hlo + off);
    float4 v;
    v.x = b2f(h.x) + b2f(l.x);
    v.y = b2f(h.y) + b2f(l.y);
    v.z = b2f(h.z) + b2f(l.z);
    v.w = b2f(h.w) + b2f(l.w);
    *(float4*)&As[r][c4 * 4] = v;
  }
  __syncthreads();

  const int r = t & 63;
  const int g = t >> 6;
  const bool isV = g >= 2;
  const int st = (g & 1) ? 9 : 0;
  const int cnt = (g & 1) ? 8 : 9;
  const float* __restrict__ W = isV ? Wr : Wl;

  float acc[9];
#pragma unroll
  for (int j = 0; j < 9; ++j) {
    int jj = st + j; if (jj > 16) jj = 16;
    acc[j] = isV ? bias[jj] : 0.f;
  }

#pragma unroll 4
  for (int k4 = 0; k4 < 32; ++k4) {
    float4 a = *(const float4*)&As[r][k4 * 4];
    const float* w0 = W + (size_t)(k4 * 4) * DO + st;
#pragma unroll
    for (int j = 0; j < 9; ++j) {
      int jc = (st + j > 16) ? (16 - st) : j;
      acc[j] = fmaf(a.x, w0[jc], acc[j]);
      acc[j] = fmaf(a.y, w0[DO + jc], acc[j]);
      acc[j] = fmaf(a.z, w0[2 * DO + jc], acc[j]);
      acc[j] = fmaf(a.w, w0[3 * DO + jc], acc[j]);
    }
  }

  float* __restrict__ dstbuf = isV ? V : U;
  const size_t base = (size_t)(row0 + r) * DO + st;
#pragma unroll
  for (int j = 0; j < 9; ++j)
    if (j < cnt) dstbuf[base + j] = acc[j];
}

// ---------------- 17-dim aggregation + epilogue (layer 4) ----------------

__global__ __launch_bounds__(256) void k_agg17(const float* __restrict__ U,
                                               const float* __restrict__ V,
                                               const int* __restrict__ cursor,
                                               const unsigned short* __restrict__ csr,
                                               float* __restrict__ out) {
  int t = blockIdx.x * 256 + threadIdx.x;
  int node = t / DO;
  if (node >= NN) return;
  int ch = t - node * DO;
  int deg = cursor[node];
  int cnt = deg > SLOTS ? SLOTS : deg;
  const unsigned short* idx = csr + ((size_t)node << 6);
  float acc = 0.f;
#define GATH(S, COND) if (COND) acc += U[(size_t)(S)*DO + ch];
  for (int base = 0; base < cnt; base += 8) {
    ushort4 i0 = *(const ushort4*)(idx + base);
    ushort4 i1 = *(const ushort4*)(idx + base + 4);
    GATH(i0.x, true)
    GATH(i0.y, base + 1 < cnt)
    GATH(i0.z, base + 2 < cnt)
    GATH(i0.w, base + 3 < cnt)
    GATH(i1.x, base + 4 < cnt)
    GATH(i1.y, base + 5 < cnt)
    GATH(i1.z, base + 6 < cnt)
    GATH(i1.w, base + 7 < cnt)
  }
#undef GATH
  float inv = 1.0f / (float)(deg > 0 ? deg : 1);
  out[(size_t)node * DO + ch] = fmaxf(fmaf(acc, inv, V[(size_t)node * DO + ch]), 0.f);
}

// ---------------- launch ----------------

extern "C" void kernel_launch(void* const* d_in, const int* in_sizes, int n_in,
                              void* d_out, int out_size, void* d_ws, size_t ws_size,
                              hipStream_t stream) {
  const float* x = (const float*)d_in[0];
  const int* ei = (const int*)d_in[1];  // [2][NE] int32
  const int* src = ei;
  const int* dst = ei + NE;
  const float *wl[5], *bl[5], *wr[5];
  for (int i = 0; i < 5; ++i) {
    wl[i] = (const float*)d_in[2 + 3 * i];
    bl[i] = (const float*)d_in[3 + 3 * i];
    wr[i] = (const float*)d_in[4 + 3 * i];
  }

  char* ws = (char*)d_ws;
  int* cursor = (int*)ws;                      ws += 160256;
  unsigned short* csr = (unsigned short*)ws;   ws += (size_t)NN * SLOTS * 2;    // 5.12 MB
  unsigned short* Hhi0 = (unsigned short*)ws;  ws += (size_t)NN * DH * 2;       // 10.24 MB
  unsigned short* Hlo0 = (unsigned short*)ws;  ws += (size_t)NN * DH * 2;
  unsigned short* Hhi1 = (unsigned short*)ws;  ws += (size_t)NN * DH * 2;
  unsigned short* Hlo1 = (unsigned short*)ws;  ws += (size_t)NN * DH * 2;
  unsigned short* WThi = (unsigned short*)ws;  ws += (size_t)4 * 128 * 256 * 2; // 256 KB
  unsigned short* WTlo = (unsigned short*)ws;  ws += (size_t)4 * 128 * 256 * 2;
  float* U = (float*)ws;                       ws += (size_t)NN * DO * 4;       // 2.72 MB
  float* V = (float*)ws;                       ws += (size_t)NN * DO * 4;

  hipMemsetAsync(cursor, 0, NN * sizeof(int), stream);
  k_fill<<<(NE + 255) / 256, 256, 0, stream>>>(src, dst, cursor, csr);
  k_tobf16<<<(NN * 32 + 255) / 256, 256, 0, stream>>>(x, Hhi0, Hlo0);
  for (int l = 0; l < 4; ++l)
    k_splitw<<<128, 256, 0, stream>>>(wl[l], wr[l], WThi + (size_t)l * 32768,
                                      WTlo + (size_t)l * 32768);

  const int GEMM_GRID = NN / 32;  // 1250
  const unsigned short* hi_in[2] = {Hhi0, Hhi1};
  const unsigned short* lo_in[2] = {Hlo0, Hlo1};
  unsigned short* hi_out[2] = {Hhi1, Hhi0};
  unsigned short* lo_out[2] = {Hlo1, Hlo0};

  for (int l = 0; l < 4; ++l) {
    int p = l & 1;
    k_layer<<<GEMM_GRID, 256, 0, stream>>>(hi_in[p], lo_in[p],
                                           WThi + (size_t)l * 32768,
                                           WTlo + (size_t)l * 32768,
                                           bl[l], cursor, csr,
                                           hi_out[p], lo_out[p]);
  }
  // after 4 layers h lives in plane 0
  k_lastproj<<<NN / 64, 256, 0, stream>>>(Hhi0, Hlo0, wl[4], wr[4], bl[4], U, V);
  k_agg17<<<(NN * DO + 255) / 256, 256, 0, stream>>>(U, V, cursor, csr,
                                                     (float*)d_out);
}

// Round 12
// 380.036 us; speedup vs baseline: 1.4004x; 1.4004x over previous
//
#include <hip/hip_runtime.h>

#define NN 40000
#define NE 640000
#define DH 128
#define DO 17
#define SLOTS 64

typedef __attribute__((ext_vector_type(8))) short short8v;
typedef __attribute__((ext_vector_type(4))) float f32x4;

__device__ inline float b2f(unsigned short u) {
  union { unsigned int i; float f; } c;
  c.i = (unsigned int)u << 16;
  return c.f;
}
__device__ inline unsigned short f2b(float f) {
  union { float f; unsigned int i; } c;
  c.f = f;
  unsigned int r = c.i + 0x7fff + ((c.i >> 16) & 1);  // RNE
  return (unsigned short)(r >> 16);
}

// ---------------- CSR build ----------------

__global__ void k_fill(const int* __restrict__ src, const int* __restrict__ dst,
                       int* __restrict__ cursor, unsigned short* __restrict__ csr) {
  int e = blockIdx.x * blockDim.x + threadIdx.x;
  if (e >= NE) return;
  int d = dst[e];
  int pos = atomicAdd(&cursor[d], 1);
  if (pos < SLOTS) csr[(d << 6) + pos] = (unsigned short)src[e];
}

// ---------------- x -> hi/lo bf16 planes ----------------

__global__ __launch_bounds__(256) void k_tobf16(const float* __restrict__ x,
                                                unsigned short* __restrict__ hi,
                                                unsigned short* __restrict__ lo) {
  int t = blockIdx.x * 256 + threadIdx.x;
  if (t >= NN * 32) return;
  float4 v = *(const float4*)(x + (size_t)t * 4);
  ushort4 h, l;
  h.x = f2b(v.x); l.x = f2b(v.x - b2f(h.x));
  h.y = f2b(v.y); l.y = f2b(v.y - b2f(h.y));
  h.z = f2b(v.z); l.z = f2b(v.z - b2f(h.z));
  h.w = f2b(v.w); l.w = f2b(v.w - b2f(h.w));
  *(ushort4*)(hi + (size_t)t * 4) = h;
  *(ushort4*)(lo + (size_t)t * 4) = l;
}

// ---------------- weight transpose + split ----------------

__global__ __launch_bounds__(256) void k_splitw(const float* __restrict__ Wl,
                                                const float* __restrict__ Wr,
                                                unsigned short* __restrict__ Thi,
                                                unsigned short* __restrict__ Tlo) {
  int n = blockIdx.x;   // 0..127
  int k = threadIdx.x;  // 0..255
  float v = (k < 128) ? Wl[(size_t)k * 128 + n] : Wr[(size_t)(k - 128) * 128 + n];
  unsigned short hi = f2b(v);
  unsigned short lo = f2b(v - b2f(hi));
  Thi[(size_t)n * 256 + k] = hi;
  Tlo[(size_t)n * 256 + k] = lo;
}

// ---------------- mean aggregation: bf16 rows, 16-deep MLP ----------------
// 2 nodes/wave, 32 lanes x 8B per row. Per iteration: 16 slot indices, 16
// UNCONDITIONAL row loads (OOB edges clamped to slot0 -> L1-hit dup), then
// conditional accumulate. Typical deg<=16: single iteration.

__global__ __launch_bounds__(256) void k_agg(const unsigned short* __restrict__ in,
                                             float* __restrict__ mean,
                                             const int* __restrict__ cursor,
                                             const unsigned short* __restrict__ csr) {
  int t = blockIdx.x * 256 + threadIdx.x;
  int node = t >> 5;
  if (node >= NN) return;
  int ch = threadIdx.x & 31;
  int deg = cursor[node];
  int cnt = deg > SLOTS ? SLOTS : deg;
  const ushort4* in4 = (const ushort4*)in;
  const unsigned short* idx = csr + ((size_t)node << 6);
  float ax = 0.f, ay = 0.f, az = 0.f, aw = 0.f;

  if (cnt > 0) {
    const int s0 = idx[0];
    for (int b = 0; b < cnt; b += 16) {
      ushort4 i0 = *(const ushort4*)(idx + b);
      ushort4 i1 = *(const ushort4*)(idx + b + 4);
      ushort4 i2 = *(const ushort4*)(idx + b + 8);
      ushort4 i3 = *(const ushort4*)(idx + b + 12);
      int s[16];
      s[0]  = i0.x;                         // b+0 < cnt always (loop cond)
      s[1]  = (b + 1  < cnt) ? i0.y : s0;
      s[2]  = (b + 2  < cnt) ? i0.z : s0;
      s[3]  = (b + 3  < cnt) ? i0.w : s0;
      s[4]  = (b + 4  < cnt) ? i1.x : s0;
      s[5]  = (b + 5  < cnt) ? i1.y : s0;
      s[6]  = (b + 6  < cnt) ? i1.z : s0;
      s[7]  = (b + 7  < cnt) ? i1.w : s0;
      s[8]  = (b + 8  < cnt) ? i2.x : s0;
      s[9]  = (b + 9  < cnt) ? i2.y : s0;
      s[10] = (b + 10 < cnt) ? i2.z : s0;
      s[11] = (b + 11 < cnt) ? i2.w : s0;
      s[12] = (b + 12 < cnt) ? i3.x : s0;
      s[13] = (b + 13 < cnt) ? i3.y : s0;
      s[14] = (b + 14 < cnt) ? i3.z : s0;
      s[15] = (b + 15 < cnt) ? i3.w : s0;
      ushort4 v[16];
#pragma unroll
      for (int k = 0; k < 16; ++k) v[k] = in4[(size_t)s[k] * 32 + ch];
#pragma unroll
      for (int k = 0; k < 16; ++k) {
        if (b + k < cnt) {
          ax += b2f(v[k].x); ay += b2f(v[k].y);
          az += b2f(v[k].z); aw += b2f(v[k].w);
        }
      }
    }
  }
  float inv = 1.0f / (float)(deg > 0 ? deg : 1);
  float4 o; o.x = ax * inv; o.y = ay * inv; o.z = az * inv; o.w = aw * inv;
  *(float4*)(mean + (size_t)node * 128 + ch * 4) = o;
}

// ---------------- MFMA GEMM: h' = relu([M|h] @ WT^T + b), split-bf16 ----------------
// BM=32, BN=128, 4 waves, 1250 blocks. In-place h update (block owns rows).

__global__ __launch_bounds__(256) void k_gemm_mfma(
    const float* __restrict__ Mn,
    const unsigned short* Hhi, const unsigned short* Hlo,   // no restrict: alias out
    const unsigned short* __restrict__ WThi,
    const unsigned short* __restrict__ WTlo,
    const float* __restrict__ bias,
    unsigned short* Ohi, unsigned short* Olo) {
  __shared__ unsigned short Ah[32][40];
  __shared__ unsigned short Al[32][40];
  __shared__ unsigned short Bh[128][40];
  __shared__ unsigned short Bl[128][40];
  const int tid = threadIdx.x;
  const int row0 = blockIdx.x * 32;
  const int w = tid >> 6;
  const int lane = tid & 63;
  const int li = lane & 15;
  const int lg = lane >> 4;

  f32x4 acc00 = {0.f, 0.f, 0.f, 0.f};
  f32x4 acc01 = acc00, acc10 = acc00, acc11 = acc00;

  const int ar = tid >> 3, af = tid & 7;
  const int bc = tid >> 1, bs = (tid & 1) * 16;

  for (int kc = 0; kc < 8; ++kc) {
    ushort4 a_hi, a_lo;
    if (kc < 4) {
      float4 v = *(const float4*)(Mn + (size_t)(row0 + ar) * 128 + kc * 32 + af * 4);
      a_hi.x = f2b(v.x); a_lo.x = f2b(v.x - b2f(a_hi.x));
      a_hi.y = f2b(v.y); a_lo.y = f2b(v.y - b2f(a_hi.y));
      a_hi.z = f2b(v.z); a_lo.z = f2b(v.z - b2f(a_hi.z));
      a_hi.w = f2b(v.w); a_lo.w = f2b(v.w - b2f(a_hi.w));
    } else {
      size_t off = (size_t)(row0 + ar) * 128 + (kc - 4) * 32 + af * 4;
      a_hi = *(const ushort4*)(Hhi + off);
      a_lo = *(const ushort4*)(Hlo + off);
    }
    size_t woff = (size_t)bc * 256 + kc * 32 + bs;
    uint4 b_h0 = *(const uint4*)(WThi + woff);
    uint4 b_h1 = *(const uint4*)(WThi + woff + 8);
    uint4 b_l0 = *(const uint4*)(WTlo + woff);
    uint4 b_l1 = *(const uint4*)(WTlo + woff + 8);
    __syncthreads();
    *(ushort4*)&Ah[ar][af * 4] = a_hi;
    *(ushort4*)&Al[ar][af * 4] = a_lo;
    *(uint4*)&Bh[bc][bs] = b_h0;
    *(uint4*)&Bh[bc][bs + 8] = b_h1;
    *(uint4*)&Bl[bc][bs] = b_l0;
    *(uint4*)&Bl[bc][bs + 8] = b_l1;
    __syncthreads();
    short8v a0h = *(const short8v*)&Ah[li][lg * 8];
    short8v a1h = *(const short8v*)&Ah[16 + li][lg * 8];
    short8v a0l = *(const short8v*)&Al[li][lg * 8];
    short8v a1l = *(const short8v*)&Al[16 + li][lg * 8];
    short8v b0h = *(const short8v*)&Bh[w * 32 + li][lg * 8];
    short8v b1h = *(const short8v*)&Bh[w * 32 + 16 + li][lg * 8];
    short8v b0l = *(const short8v*)&Bl[w * 32 + li][lg * 8];
    short8v b1l = *(const short8v*)&Bl[w * 32 + 16 + li][lg * 8];
    acc00 = __builtin_amdgcn_mfma_f32_16x16x32_bf16(a0h, b0h, acc00, 0, 0, 0);
    acc00 = __builtin_amdgcn_mfma_f32_16x16x32_bf16(a0l, b0h, acc00, 0, 0, 0);
    acc00 = __builtin_amdgcn_mfma_f32_16x16x32_bf16(a0h, b0l, acc00, 0, 0, 0);
    acc01 = __builtin_amdgcn_mfma_f32_16x16x32_bf16(a0h, b1h, acc01, 0, 0, 0);
    acc01 = __builtin_amdgcn_mfma_f32_16x16x32_bf16(a0l, b1h, acc01, 0, 0, 0);
    acc01 = __builtin_amdgcn_mfma_f32_16x16x32_bf16(a0h, b1l, acc01, 0, 0, 0);
    acc10 = __builtin_amdgcn_mfma_f32_16x16x32_bf16(a1h, b0h, acc10, 0, 0, 0);
    acc10 = __builtin_amdgcn_mfma_f32_16x16x32_bf16(a1l, b0h, acc10, 0, 0, 0);
    acc10 = __builtin_amdgcn_mfma_f32_16x16x32_bf16(a1h, b0l, acc10, 0, 0, 0);
    acc11 = __builtin_amdgcn_mfma_f32_16x16x32_bf16(a1h, b1h, acc11, 0, 0, 0);
    acc11 = __builtin_amdgcn_mfma_f32_16x16x32_bf16(a1l, b1h, acc11, 0, 0, 0);
    acc11 = __builtin_amdgcn_mfma_f32_16x16x32_bf16(a1h, b1l, acc11, 0, 0, 0);
  }

  // epilogue: C/D layout col=lane&15, row=(lane>>4)*4+reg
  const int c0 = w * 32 + li;
  const float bv0 = bias[c0];
  const float bv1 = bias[c0 + 16];
#pragma unroll
  for (int reg = 0; reg < 4; ++reg) {
    int r0 = row0 + lg * 4 + reg;
    int r1 = r0 + 16;
    float v;
    unsigned short h;
    v = acc00[reg] + bv0; v = v > 0.f ? v : 0.f;
    h = f2b(v); Ohi[(size_t)r0 * 128 + c0] = h; Olo[(size_t)r0 * 128 + c0] = f2b(v - b2f(h));
    v = acc01[reg] + bv1; v = v > 0.f ? v : 0.f;
    h = f2b(v); Ohi[(size_t)r0 * 128 + c0 + 16] = h; Olo[(size_t)r0 * 128 + c0 + 16] = f2b(v - b2f(h));
    v = acc10[reg] + bv0; v = v > 0.f ? v : 0.f;
    h = f2b(v); Ohi[(size_t)r1 * 128 + c0] = h; Olo[(size_t)r1 * 128 + c0] = f2b(v - b2f(h));
    v = acc11[reg] + bv1; v = v > 0.f ? v : 0.f;
    h = f2b(v); Ohi[(size_t)r1 * 128 + c0 + 16] = h; Olo[(size_t)r1 * 128 + c0 + 16] = f2b(v - b2f(h));
  }
}

// ---------------- layer-4 projection from hi/lo planes ----------------

__global__ __launch_bounds__(256) void k_lastproj(const unsigned short* __restrict__ Hhi,
                                                  const unsigned short* __restrict__ Hlo,
                                                  const float* __restrict__ Wl,
                                                  const float* __restrict__ Wr,
                                                  const float* __restrict__ bias,
                                                  float* __restrict__ U,
                                                  float* __restrict__ V) {
  __shared__ float As[64][132];
  const int t = threadIdx.x;
  const int row0 = blockIdx.x * 64;

#pragma unroll
  for (int i = 0; i < 8; ++i) {
    int idx = i * 256 + t;
    int r = idx >> 5, c4 = idx & 31;
    size_t off = (size_t)(row0 + r) * 128 + c4 * 4;
    ushort4 h = *(const ushort4*)(Hhi + off);
    ushort4 l = *(const ushort4*)(Hlo + off);
    float4 v;
    v.x = b2f(h.x) + b2f(l.x);
    v.y = b2f(h.y) + b2f(l.y);
    v.z = b2f(h.z) + b2f(l.z);
    v.w = b2f(h.w) + b2f(l.w);
    *(float4*)&As[r][c4 * 4] = v;
  }
  __syncthreads();

  const int r = t & 63;
  const int g = t >> 6;
  const bool isV = g >= 2;
  const int st = (g & 1) ? 9 : 0;
  const int cnt = (g & 1) ? 8 : 9;
  const float* __restrict__ W = isV ? Wr : Wl;

  float acc[9];
#pragma unroll
  for (int j = 0; j < 9; ++j) {
    int jj = st + j; if (jj > 16) jj = 16;
    acc[j] = isV ? bias[jj] : 0.f;
  }

#pragma unroll 4
  for (int k4 = 0; k4 < 32; ++k4) {
    float4 a = *(const float4*)&As[r][k4 * 4];
    const float* w0 = W + (size_t)(k4 * 4) * DO + st;
#pragma unroll
    for (int j = 0; j < 9; ++j) {
      int jc = (st + j > 16) ? (16 - st) : j;
      acc[j] = fmaf(a.x, w0[jc], acc[j]);
      acc[j] = fmaf(a.y, w0[DO + jc], acc[j]);
      acc[j] = fmaf(a.z, w0[2 * DO + jc], acc[j]);
      acc[j] = fmaf(a.w, w0[3 * DO + jc], acc[j]);
    }
  }

  float* __restrict__ dstbuf = isV ? V : U;
  const size_t base = (size_t)(row0 + r) * DO + st;
#pragma unroll
  for (int j = 0; j < 9; ++j)
    if (j < cnt) dstbuf[base + j] = acc[j];
}

// ---------------- 17-dim aggregation + epilogue (layer 4) ----------------

__global__ __launch_bounds__(256) void k_agg17(const float* __restrict__ U,
                                               const float* __restrict__ V,
                                               const int* __restrict__ cursor,
                                               const unsigned short* __restrict__ csr,
                                               float* __restrict__ out) {
  int t = blockIdx.x * 256 + threadIdx.x;
  int node = t / DO;
  if (node >= NN) return;
  int ch = t - node * DO;
  int deg = cursor[node];
  int cnt = deg > SLOTS ? SLOTS : deg;
  const unsigned short* idx = csr + ((size_t)node << 6);
  float acc = 0.f;
#define GATH(S, COND) if (COND) acc += U[(size_t)(S)*DO + ch];
  for (int base = 0; base < cnt; base += 8) {
    ushort4 i0 = *(const ushort4*)(idx + base);
    ushort4 i1 = *(const ushort4*)(idx + base + 4);
    GATH(i0.x, true)
    GATH(i0.y, base + 1 < cnt)
    GATH(i0.z, base + 2 < cnt)
    GATH(i0.w, base + 3 < cnt)
    GATH(i1.x, base + 4 < cnt)
    GATH(i1.y, base + 5 < cnt)
    GATH(i1.z, base + 6 < cnt)
    GATH(i1.w, base + 7 < cnt)
  }
#undef GATH
  float inv = 1.0f / (float)(deg > 0 ? deg : 1);
  out[(size_t)node * DO + ch] = fmaxf(fmaf(acc, inv, V[(size_t)node * DO + ch]), 0.f);
}

// ---------------- launch ----------------

extern "C" void kernel_launch(void* const* d_in, const int* in_sizes, int n_in,
                              void* d_out, int out_size, void* d_ws, size_t ws_size,
                              hipStream_t stream) {
  const float* x = (const float*)d_in[0];
  const int* ei = (const int*)d_in[1];  // [2][NE] int32
  const int* src = ei;
  const int* dst = ei + NE;
  const float *wl[5], *bl[5], *wr[5];
  for (int i = 0; i < 5; ++i) {
    wl[i] = (const float*)d_in[2 + 3 * i];
    bl[i] = (const float*)d_in[3 + 3 * i];
    wr[i] = (const float*)d_in[4 + 3 * i];
  }

  char* ws = (char*)d_ws;
  int* cursor = (int*)ws;                      ws += 160256;
  unsigned short* csr = (unsigned short*)ws;   ws += (size_t)NN * SLOTS * 2;  // 5.12 MB
  unsigned short* Hhi = (unsigned short*)ws;   ws += (size_t)NN * DH * 2;     // 10.24 MB
  unsigned short* Hlo = (unsigned short*)ws;   ws += (size_t)NN * DH * 2;     // 10.24 MB
  unsigned short* WThi = (unsigned short*)ws;  ws += (size_t)4 * 128 * 256 * 2;  // 256 KB
  unsigned short* WTlo = (unsigned short*)ws;  ws += (size_t)4 * 128 * 256 * 2;  // 256 KB
  float* M = (float*)ws;                       ws += (size_t)NN * DH * 4;     // 20.48 MB
  float* U = M;   // M dead by layer 4
  float* V = M + (size_t)NN * DO;

  hipMemsetAsync(cursor, 0, NN * sizeof(int), stream);
  k_fill<<<(NE + 255) / 256, 256, 0, stream>>>(src, dst, cursor, csr);
  k_tobf16<<<(NN * 32 + 255) / 256, 256, 0, stream>>>(x, Hhi, Hlo);
  for (int l = 0; l < 4; ++l)
    k_splitw<<<128, 256, 0, stream>>>(wl[l], wr[l], WThi + (size_t)l * 32768,
                                      WTlo + (size_t)l * 32768);

  const int AGG_GRID = (NN * 32 + 255) / 256;  // 5000
  const int GEMM_GRID = NN / 32;               // 1250

  for (int l = 0; l < 4; ++l) {
    k_agg<<<AGG_GRID, 256, 0, stream>>>(Hhi, M, cursor, csr);
    k_gemm_mfma<<<GEMM_GRID, 256, 0, stream>>>(M, Hhi, Hlo,
                                               WThi + (size_t)l * 32768,
                                               WTlo + (size_t)l * 32768,
                                               bl[l], Hhi, Hlo);
  }
  // L4
  k_lastproj<<<NN / 64, 256, 0, stream>>>(Hhi, Hlo, wl[4], wr[4], bl[4], U, V);
  k_agg17<<<(NN * DO + 255) / 256, 256, 0, stream>>>(U, V, cursor, csr,
                                                     (float*)d_out);
}

// Round 13
// 377.102 us; speedup vs baseline: 1.4113x; 1.0078x over previous
//
#include <hip/hip_runtime.h>

#define NN 40000
#define NE 640000
#define DH 128
#define DO 17
#define SLOTS 64

typedef __attribute__((ext_vector_type(8))) short short8v;
typedef __attribute__((ext_vector_type(4))) float f32x4;

__device__ inline float b2f(unsigned short u) {
  union { unsigned int i; float f; } c;
  c.i = (unsigned int)u << 16;
  return c.f;
}
__device__ inline unsigned short f2b(float f) {
  union { float f; unsigned int i; } c;
  c.f = f;
  unsigned int r = c.i + 0x7fff + ((c.i >> 16) & 1);  // RNE
  return (unsigned short)(r >> 16);
}

// ---------------- CSR build ----------------

__global__ void k_fill(const int* __restrict__ src, const int* __restrict__ dst,
                       int* __restrict__ cursor, unsigned short* __restrict__ csr) {
  int e = blockIdx.x * blockDim.x + threadIdx.x;
  if (e >= NE) return;
  int d = dst[e];
  int pos = atomicAdd(&cursor[d], 1);
  if (pos < SLOTS) csr[(d << 6) + pos] = (unsigned short)src[e];
}

// ---------------- x -> hi/lo bf16 planes ----------------

__global__ __launch_bounds__(256) void k_tobf16(const float* __restrict__ x,
                                                unsigned short* __restrict__ hi,
                                                unsigned short* __restrict__ lo) {
  int t = blockIdx.x * 256 + threadIdx.x;
  if (t >= NN * 32) return;
  float4 v = *(const float4*)(x + (size_t)t * 4);
  ushort4 h, l;
  h.x = f2b(v.x); l.x = f2b(v.x - b2f(h.x));
  h.y = f2b(v.y); l.y = f2b(v.y - b2f(h.y));
  h.z = f2b(v.z); l.z = f2b(v.z - b2f(h.z));
  h.w = f2b(v.w); l.w = f2b(v.w - b2f(h.w));
  *(ushort4*)(hi + (size_t)t * 4) = h;
  *(ushort4*)(lo + (size_t)t * 4) = l;
}

// ---------------- weight transpose + split ----------------

__global__ __launch_bounds__(256) void k_splitw(const float* __restrict__ Wl,
                                                const float* __restrict__ Wr,
                                                unsigned short* __restrict__ Thi,
                                                unsigned short* __restrict__ Tlo) {
  int n = blockIdx.x;   // 0..127
  int k = threadIdx.x;  // 0..255
  float v = (k < 128) ? Wl[(size_t)k * 128 + n] : Wr[(size_t)(k - 128) * 128 + n];
  unsigned short hi = f2b(v);
  unsigned short lo = f2b(v - b2f(hi));
  Thi[(size_t)n * 256 + k] = hi;
  Tlo[(size_t)n * 256 + k] = lo;
}

// ---------------- mean aggregation: bf16 rows, 16-deep MLP ----------------
// Output written directly as hi/lo bf16 split planes (same RNE split the GEMM
// used to do on the fp32 mean -> bit-identical numerics, no fp32 M buffer).

__global__ __launch_bounds__(256) void k_agg(const unsigned short* __restrict__ in,
                                             unsigned short* __restrict__ Mhi,
                                             unsigned short* __restrict__ Mlo,
                                             const int* __restrict__ cursor,
                                             const unsigned short* __restrict__ csr) {
  int t = blockIdx.x * 256 + threadIdx.x;
  int node = t >> 5;
  if (node >= NN) return;
  int ch = threadIdx.x & 31;
  int deg = cursor[node];
  int cnt = deg > SLOTS ? SLOTS : deg;
  const ushort4* in4 = (const ushort4*)in;
  const unsigned short* idx = csr + ((size_t)node << 6);
  float ax = 0.f, ay = 0.f, az = 0.f, aw = 0.f;

  if (cnt > 0) {
    const int s0 = idx[0];
    for (int b = 0; b < cnt; b += 16) {
      ushort4 i0 = *(const ushort4*)(idx + b);
      ushort4 i1 = *(const ushort4*)(idx + b + 4);
      ushort4 i2 = *(const ushort4*)(idx + b + 8);
      ushort4 i3 = *(const ushort4*)(idx + b + 12);
      int s[16];
      s[0]  = i0.x;
      s[1]  = (b + 1  < cnt) ? i0.y : s0;
      s[2]  = (b + 2  < cnt) ? i0.z : s0;
      s[3]  = (b + 3  < cnt) ? i0.w : s0;
      s[4]  = (b + 4  < cnt) ? i1.x : s0;
      s[5]  = (b + 5  < cnt) ? i1.y : s0;
      s[6]  = (b + 6  < cnt) ? i1.z : s0;
      s[7]  = (b + 7  < cnt) ? i1.w : s0;
      s[8]  = (b + 8  < cnt) ? i2.x : s0;
      s[9]  = (b + 9  < cnt) ? i2.y : s0;
      s[10] = (b + 10 < cnt) ? i2.z : s0;
      s[11] = (b + 11 < cnt) ? i2.w : s0;
      s[12] = (b + 12 < cnt) ? i3.x : s0;
      s[13] = (b + 13 < cnt) ? i3.y : s0;
      s[14] = (b + 14 < cnt) ? i3.z : s0;
      s[15] = (b + 15 < cnt) ? i3.w : s0;
      ushort4 v[16];
#pragma unroll
      for (int k = 0; k < 16; ++k) v[k] = in4[(size_t)s[k] * 32 + ch];
#pragma unroll
      for (int k = 0; k < 16; ++k) {
        if (b + k < cnt) {
          ax += b2f(v[k].x); ay += b2f(v[k].y);
          az += b2f(v[k].z); aw += b2f(v[k].w);
        }
      }
    }
  }
  float inv = 1.0f / (float)(deg > 0 ? deg : 1);
  ax *= inv; ay *= inv; az *= inv; aw *= inv;
  ushort4 h, l;
  h.x = f2b(ax); l.x = f2b(ax - b2f(h.x));
  h.y = f2b(ay); l.y = f2b(ay - b2f(h.y));
  h.z = f2b(az); l.z = f2b(az - b2f(h.z));
  h.w = f2b(aw); l.w = f2b(aw - b2f(h.w));
  *(ushort4*)(Mhi + (size_t)node * 128 + ch * 4) = h;
  *(ushort4*)(Mlo + (size_t)node * 128 + ch * 4) = l;
}

// ---------------- MFMA GEMM v2: h' = relu([M|h] @ WT^T + b), split-bf16 ----------------
// BM=64, BN=128, 4 waves in 2x2 quadrants (wave = 32 rows x 64 cols), 625
// blocks. A-path uniform ushort planes (M for kc<4, h for kc>=4). In-place h
// update (block owns its 64 rows).

__global__ __launch_bounds__(256) void k_gemm_mfma(
    const unsigned short* __restrict__ Mhi,
    const unsigned short* __restrict__ Mlo,
    const unsigned short* Hhi, const unsigned short* Hlo,   // no restrict: alias out
    const unsigned short* __restrict__ WThi,
    const unsigned short* __restrict__ WTlo,
    const float* __restrict__ bias,
    unsigned short* Ohi, unsigned short* Olo) {
  __shared__ unsigned short Ah[64][40];   // 80B rows: 16B-aligned
  __shared__ unsigned short Al[64][40];
  __shared__ unsigned short Bh[128][40];
  __shared__ unsigned short Bl[128][40];
  const int tid = threadIdx.x;
  const int row0 = blockIdx.x * 64;
  const int w = tid >> 6;
  const int lane = tid & 63;
  const int li = lane & 15;
  const int lg = lane >> 4;
  const int wr = (w & 1) * 32;    // wave row base within tile
  const int wc = (w >> 1) * 64;   // wave col base within tile

  f32x4 acc[2][4];
#pragma unroll
  for (int i = 0; i < 2; ++i)
#pragma unroll
    for (int j = 0; j < 4; ++j) acc[i][j] = (f32x4){0.f, 0.f, 0.f, 0.f};

  const int ar = tid >> 2, af = tid & 3;         // A stage: row 0..63, 8-ushort seg
  const int bc = tid >> 1, bs = (tid & 1) * 16;  // B stage: col 0..127, 16-ushort half

  for (int kc = 0; kc < 8; ++kc) {
    const unsigned short* Phi = (kc < 4) ? Mhi : Hhi;
    const unsigned short* Plo = (kc < 4) ? Mlo : Hlo;
    size_t aoff = (size_t)(row0 + ar) * 128 + (kc & 3) * 32 + af * 8;
    uint4 a_h = *(const uint4*)(Phi + aoff);
    uint4 a_l = *(const uint4*)(Plo + aoff);
    size_t woff = (size_t)bc * 256 + kc * 32 + bs;
    uint4 b_h0 = *(const uint4*)(WThi + woff);
    uint4 b_h1 = *(const uint4*)(WThi + woff + 8);
    uint4 b_l0 = *(const uint4*)(WTlo + woff);
    uint4 b_l1 = *(const uint4*)(WTlo + woff + 8);
    __syncthreads();
    *(uint4*)&Ah[ar][af * 8] = a_h;
    *(uint4*)&Al[ar][af * 8] = a_l;
    *(uint4*)&Bh[bc][bs] = b_h0;
    *(uint4*)&Bh[bc][bs + 8] = b_h1;
    *(uint4*)&Bl[bc][bs] = b_l0;
    *(uint4*)&Bl[bc][bs + 8] = b_l1;
    __syncthreads();
    short8v ah[2], al2[2], bfh[4], bfl[4];
#pragma unroll
    for (int rf = 0; rf < 2; ++rf) {
      ah[rf]  = *(const short8v*)&Ah[wr + rf * 16 + li][lg * 8];
      al2[rf] = *(const short8v*)&Al[wr + rf * 16 + li][lg * 8];
    }
#pragma unroll
    for (int cf = 0; cf < 4; ++cf) {
      bfh[cf] = *(const short8v*)&Bh[wc + cf * 16 + li][lg * 8];
      bfl[cf] = *(const short8v*)&Bl[wc + cf * 16 + li][lg * 8];
    }
#pragma unroll
    for (int rf = 0; rf < 2; ++rf)
#pragma unroll
      for (int cf = 0; cf < 4; ++cf) {
        acc[rf][cf] = __builtin_amdgcn_mfma_f32_16x16x32_bf16(ah[rf], bfh[cf], acc[rf][cf], 0, 0, 0);
        acc[rf][cf] = __builtin_amdgcn_mfma_f32_16x16x32_bf16(al2[rf], bfh[cf], acc[rf][cf], 0, 0, 0);
        acc[rf][cf] = __builtin_amdgcn_mfma_f32_16x16x32_bf16(ah[rf], bfl[cf], acc[rf][cf], 0, 0, 0);
      }
  }

  // epilogue: C/D layout col=lane&15, row=(lane>>4)*4+reg
#pragma unroll
  for (int rf = 0; rf < 2; ++rf) {
#pragma unroll
    for (int cf = 0; cf < 4; ++cf) {
      int c = wc + cf * 16 + li;
      float bv = bias[c];
#pragma unroll
      for (int reg = 0; reg < 4; ++reg) {
        int r = row0 + wr + rf * 16 + lg * 4 + reg;
        float v = acc[rf][cf][reg] + bv;
        v = v > 0.f ? v : 0.f;
        unsigned short h = f2b(v);
        Ohi[(size_t)r * 128 + c] = h;
        Olo[(size_t)r * 128 + c] = f2b(v - b2f(h));
      }
    }
  }
}

// ---------------- layer-4 projection from hi/lo planes ----------------

__global__ __launch_bounds__(256) void k_lastproj(const unsigned short* __restrict__ Hhi,
                                                  const unsigned short* __restrict__ Hlo,
                                                  const float* __restrict__ Wl,
                                                  const float* __restrict__ Wr,
                                                  const float* __restrict__ bias,
                                                  float* __restrict__ U,
                                                  float* __restrict__ V) {
  __shared__ float As[64][132];
  const int t = threadIdx.x;
  const int row0 = blockIdx.x * 64;

#pragma unroll
  for (int i = 0; i < 8; ++i) {
    int idx = i * 256 + t;
    int r = idx >> 5, c4 = idx & 31;
    size_t off = (size_t)(row0 + r) * 128 + c4 * 4;
    ushort4 h = *(const ushort4*)(Hhi + off);
    ushort4 l = *(const ushort4*)(Hlo + off);
    float4 v;
    v.x = b2f(h.x) + b2f(l.x);
    v.y = b2f(h.y) + b2f(l.y);
    v.z = b2f(h.z) + b2f(l.z);
    v.w = b2f(h.w) + b2f(l.w);
    *(float4*)&As[r][c4 * 4] = v;
  }
  __syncthreads();

  const int r = t & 63;
  const int g = t >> 6;
  const bool isV = g >= 2;
  const int st = (g & 1) ? 9 : 0;
  const int cnt = (g & 1) ? 8 : 9;
  const float* __restrict__ W = isV ? Wr : Wl;

  float acc[9];
#pragma unroll
  for (int j = 0; j < 9; ++j) {
    int jj = st + j; if (jj > 16) jj = 16;
    acc[j] = isV ? bias[jj] : 0.f;
  }

#pragma unroll 4
  for (int k4 = 0; k4 < 32; ++k4) {
    float4 a = *(const float4*)&As[r][k4 * 4];
    const float* w0 = W + (size_t)(k4 * 4) * DO + st;
#pragma unroll
    for (int j = 0; j < 9; ++j) {
      int jc = (st + j > 16) ? (16 - st) : j;
      acc[j] = fmaf(a.x, w0[jc], acc[j]);
      acc[j] = fmaf(a.y, w0[DO + jc], acc[j]);
      acc[j] = fmaf(a.z, w0[2 * DO + jc], acc[j]);
      acc[j] = fmaf(a.w, w0[3 * DO + jc], acc[j]);
    }
  }

  float* __restrict__ dstbuf = isV ? V : U;
  const size_t base = (size_t)(row0 + r) * DO + st;
#pragma unroll
  for (int j = 0; j < 9; ++j)
    if (j < cnt) dstbuf[base + j] = acc[j];
}

// ---------------- 17-dim aggregation + epilogue (layer 4) ----------------

__global__ __launch_bounds__(256) void k_agg17(const float* __restrict__ U,
                                               const float* __restrict__ V,
                                               const int* __restrict__ cursor,
                                               const unsigned short* __restrict__ csr,
                                               float* __restrict__ out) {
  int t = blockIdx.x * 256 + threadIdx.x;
  int node = t / DO;
  if (node >= NN) return;
  int ch = t - node * DO;
  int deg = cursor[node];
  int cnt = deg > SLOTS ? SLOTS : deg;
  const unsigned short* idx = csr + ((size_t)node << 6);
  float acc = 0.f;
#define GATH(S, COND) if (COND) acc += U[(size_t)(S)*DO + ch];
  for (int base = 0; base < cnt; base += 8) {
    ushort4 i0 = *(const ushort4*)(idx + base);
    ushort4 i1 = *(const ushort4*)(idx + base + 4);
    GATH(i0.x, true)
    GATH(i0.y, base + 1 < cnt)
    GATH(i0.z, base + 2 < cnt)
    GATH(i0.w, base + 3 < cnt)
    GATH(i1.x, base + 4 < cnt)
    GATH(i1.y, base + 5 < cnt)
    GATH(i1.z, base + 6 < cnt)
    GATH(i1.w, base + 7 < cnt)
  }
#undef GATH
  float inv = 1.0f / (float)(deg > 0 ? deg : 1);
  out[(size_t)node * DO + ch] = fmaxf(fmaf(acc, inv, V[(size_t)node * DO + ch]), 0.f);
}

// ---------------- launch ----------------

extern "C" void kernel_launch(void* const* d_in, const int* in_sizes, int n_in,
                              void* d_out, int out_size, void* d_ws, size_t ws_size,
                              hipStream_t stream) {
  const float* x = (const float*)d_in[0];
  const int* ei = (const int*)d_in[1];  // [2][NE] int32
  const int* src = ei;
  const int* dst = ei + NE;
  const float *wl[5], *bl[5], *wr[5];
  for (int i = 0; i < 5; ++i) {
    wl[i] = (const float*)d_in[2 + 3 * i];
    bl[i] = (const float*)d_in[3 + 3 * i];
    wr[i] = (const float*)d_in[4 + 3 * i];
  }

  char* ws = (char*)d_ws;
  int* cursor = (int*)ws;                      ws += 160256;
  unsigned short* csr = (unsigned short*)ws;   ws += (size_t)NN * SLOTS * 2;  // 5.12 MB
  unsigned short* Hhi = (unsigned short*)ws;   ws += (size_t)NN * DH * 2;     // 10.24 MB
  unsigned short* Hlo = (unsigned short*)ws;   ws += (size_t)NN * DH * 2;
  unsigned short* Mhi = (unsigned short*)ws;   ws += (size_t)NN * DH * 2;
  unsigned short* Mlo = (unsigned short*)ws;   ws += (size_t)NN * DH * 2;
  unsigned short* WThi = (unsigned short*)ws;  ws += (size_t)4 * 128 * 256 * 2;  // 256 KB
  unsigned short* WTlo = (unsigned short*)ws;  ws += (size_t)4 * 128 * 256 * 2;
  float* U = (float*)Mhi;   // M planes dead by layer 4
  float* V = U + (size_t)NN * DO;

  hipMemsetAsync(cursor, 0, NN * sizeof(int), stream);
  k_fill<<<(NE + 255) / 256, 256, 0, stream>>>(src, dst, cursor, csr);
  k_tobf16<<<(NN * 32 + 255) / 256, 256, 0, stream>>>(x, Hhi, Hlo);
  for (int l = 0; l < 4; ++l)
    k_splitw<<<128, 256, 0, stream>>>(wl[l], wr[l], WThi + (size_t)l * 32768,
                                      WTlo + (size_t)l * 32768);

  const int AGG_GRID = (NN * 32 + 255) / 256;  // 5000
  const int GEMM_GRID = NN / 64;               // 625

  for (int l = 0; l < 4; ++l) {
    k_agg<<<AGG_GRID, 256, 0, stream>>>(Hhi, Mhi, Mlo, cursor, csr);
    k_gemm_mfma<<<GEMM_GRID, 256, 0, stream>>>(Mhi, Mlo, Hhi, Hlo,
                                               WThi + (size_t)l * 32768,
                                               WTlo + (size_t)l * 32768,
                                               bl[l], Hhi, Hlo);
  }
  // L4
  k_lastproj<<<NN / 64, 256, 0, stream>>>(Hhi, Hlo, wl[4], wr[4], bl[4], U, V);
  k_agg17<<<(NN * DO + 255) / 256, 256, 0, stream>>>(U, V, cursor, csr,
                                                     (float*)d_out);
}

// Round 14
// 367.667 us; speedup vs baseline: 1.4475x; 1.0257x over previous
//
#include <hip/hip_runtime.h>

#define NN 40000
#define NE 640000
#define DH 128
#define DO 17
#define SLOTS 64

typedef __attribute__((ext_vector_type(8))) short short8v;
typedef __attribute__((ext_vector_type(4))) float f32x4;

__device__ inline float b2f(unsigned short u) {
  union { unsigned int i; float f; } c;
  c.i = (unsigned int)u << 16;
  return c.f;
}
__device__ inline unsigned short f2b(float f) {
  union { float f; unsigned int i; } c;
  c.f = f;
  unsigned int r = c.i + 0x7fff + ((c.i >> 16) & 1);  // RNE
  return (unsigned short)(r >> 16);
}

// ---------------- fused prep: CSR fill + x->hi/lo + weight split ----------------
// Grid-partitioned: [0,2500) edge fill, [2500,7500) tobf16, [7500,8012) splitw.
// Phases are independent (disjoint outputs); cursor memset precedes launch.

__global__ __launch_bounds__(256) void k_prep(
    const int* __restrict__ src, const int* __restrict__ dst,
    const float* __restrict__ x,
    const float* __restrict__ Wl0, const float* __restrict__ Wr0,
    const float* __restrict__ Wl1, const float* __restrict__ Wr1,
    const float* __restrict__ Wl2, const float* __restrict__ Wr2,
    const float* __restrict__ Wl3, const float* __restrict__ Wr3,
    int* __restrict__ cursor, unsigned short* __restrict__ csr,
    unsigned short* __restrict__ Hhi, unsigned short* __restrict__ Hlo,
    unsigned short* __restrict__ WThi, unsigned short* __restrict__ WTlo) {
  const int bid = blockIdx.x;
  const int tid = threadIdx.x;
  if (bid < 2500) {                       // ---- CSR fill ----
    int e = bid * 256 + tid;
    if (e < NE) {
      int d = dst[e];
      int pos = atomicAdd(&cursor[d], 1);
      if (pos < SLOTS) csr[(d << 6) + pos] = (unsigned short)src[e];
    }
  } else if (bid < 7500) {                // ---- x -> hi/lo planes ----
    int t = (bid - 2500) * 256 + tid;
    if (t < NN * 32) {
      float4 v = *(const float4*)(x + (size_t)t * 4);
      ushort4 h, l;
      h.x = f2b(v.x); l.x = f2b(v.x - b2f(h.x));
      h.y = f2b(v.y); l.y = f2b(v.y - b2f(h.y));
      h.z = f2b(v.z); l.z = f2b(v.z - b2f(h.z));
      h.w = f2b(v.w); l.w = f2b(v.w - b2f(h.w));
      *(ushort4*)(Hhi + (size_t)t * 4) = h;
      *(ushort4*)(Hlo + (size_t)t * 4) = l;
    }
  } else {                                // ---- weight transpose + split ----
    int q = bid - 7500;                   // 0..511
    int l = q >> 7;                       // layer
    int n = q & 127;                      // out column
    const float* Wl = (l == 0) ? Wl0 : (l == 1) ? Wl1 : (l == 2) ? Wl2 : Wl3;
    const float* Wr = (l == 0) ? Wr0 : (l == 1) ? Wr1 : (l == 2) ? Wr2 : Wr3;
    int k = tid;
    float v = (k < 128) ? Wl[(size_t)k * 128 + n] : Wr[(size_t)(k - 128) * 128 + n];
    unsigned short hi = f2b(v);
    unsigned short lo = f2b(v - b2f(hi));
    size_t base = (size_t)l * 32768 + (size_t)n * 256 + k;
    WThi[base] = hi;
    WTlo[base] = lo;
  }
}

// ---------------- mean aggregation: bf16 rows, 16-deep MLP ----------------

__global__ __launch_bounds__(256) void k_agg(const unsigned short* __restrict__ in,
                                             unsigned short* __restrict__ Mhi,
                                             unsigned short* __restrict__ Mlo,
                                             const int* __restrict__ cursor,
                                             const unsigned short* __restrict__ csr) {
  int t = blockIdx.x * 256 + threadIdx.x;
  int node = t >> 5;
  if (node >= NN) return;
  int ch = threadIdx.x & 31;
  int deg = cursor[node];
  int cnt = deg > SLOTS ? SLOTS : deg;
  const ushort4* in4 = (const ushort4*)in;
  const unsigned short* idx = csr + ((size_t)node << 6);
  float ax = 0.f, ay = 0.f, az = 0.f, aw = 0.f;

  if (cnt > 0) {
    const int s0 = idx[0];
    for (int b = 0; b < cnt; b += 16) {
      ushort4 i0 = *(const ushort4*)(idx + b);
      ushort4 i1 = *(const ushort4*)(idx + b + 4);
      ushort4 i2 = *(const ushort4*)(idx + b + 8);
      ushort4 i3 = *(const ushort4*)(idx + b + 12);
      int s[16];
      s[0]  = i0.x;
      s[1]  = (b + 1  < cnt) ? i0.y : s0;
      s[2]  = (b + 2  < cnt) ? i0.z : s0;
      s[3]  = (b + 3  < cnt) ? i0.w : s0;
      s[4]  = (b + 4  < cnt) ? i1.x : s0;
      s[5]  = (b + 5  < cnt) ? i1.y : s0;
      s[6]  = (b + 6  < cnt) ? i1.z : s0;
      s[7]  = (b + 7  < cnt) ? i1.w : s0;
      s[8]  = (b + 8  < cnt) ? i2.x : s0;
      s[9]  = (b + 9  < cnt) ? i2.y : s0;
      s[10] = (b + 10 < cnt) ? i2.z : s0;
      s[11] = (b + 11 < cnt) ? i2.w : s0;
      s[12] = (b + 12 < cnt) ? i3.x : s0;
      s[13] = (b + 13 < cnt) ? i3.y : s0;
      s[14] = (b + 14 < cnt) ? i3.z : s0;
      s[15] = (b + 15 < cnt) ? i3.w : s0;
      ushort4 v[16];
#pragma unroll
      for (int k = 0; k < 16; ++k) v[k] = in4[(size_t)s[k] * 32 + ch];
#pragma unroll
      for (int k = 0; k < 16; ++k) {
        if (b + k < cnt) {
          ax += b2f(v[k].x); ay += b2f(v[k].y);
          az += b2f(v[k].z); aw += b2f(v[k].w);
        }
      }
    }
  }
  float inv = 1.0f / (float)(deg > 0 ? deg : 1);
  ax *= inv; ay *= inv; az *= inv; aw *= inv;
  ushort4 h, l;
  h.x = f2b(ax); l.x = f2b(ax - b2f(h.x));
  h.y = f2b(ay); l.y = f2b(ay - b2f(h.y));
  h.z = f2b(az); l.z = f2b(az - b2f(h.z));
  h.w = f2b(aw); l.w = f2b(aw - b2f(h.w));
  *(ushort4*)(Mhi + (size_t)node * 128 + ch * 4) = h;
  *(ushort4*)(Mlo + (size_t)node * 128 + ch * 4) = l;
}

// ---------------- MFMA GEMM v2: h' = relu([M|h] @ WT^T + b), split-bf16 ----------------

__global__ __launch_bounds__(256) void k_gemm_mfma(
    const unsigned short* __restrict__ Mhi,
    const unsigned short* __restrict__ Mlo,
    const unsigned short* Hhi, const unsigned short* Hlo,   // no restrict: alias out
    const unsigned short* __restrict__ WThi,
    const unsigned short* __restrict__ WTlo,
    const float* __restrict__ bias,
    unsigned short* Ohi, unsigned short* Olo) {
  __shared__ unsigned short Ah[64][40];
  __shared__ unsigned short Al[64][40];
  __shared__ unsigned short Bh[128][40];
  __shared__ unsigned short Bl[128][40];
  const int tid = threadIdx.x;
  const int row0 = blockIdx.x * 64;
  const int w = tid >> 6;
  const int lane = tid & 63;
  const int li = lane & 15;
  const int lg = lane >> 4;
  const int wr = (w & 1) * 32;
  const int wc = (w >> 1) * 64;

  f32x4 acc[2][4];
#pragma unroll
  for (int i = 0; i < 2; ++i)
#pragma unroll
    for (int j = 0; j < 4; ++j) acc[i][j] = (f32x4){0.f, 0.f, 0.f, 0.f};

  const int ar = tid >> 2, af = tid & 3;
  const int bc = tid >> 1, bs = (tid & 1) * 16;

  for (int kc = 0; kc < 8; ++kc) {
    const unsigned short* Phi = (kc < 4) ? Mhi : Hhi;
    const unsigned short* Plo = (kc < 4) ? Mlo : Hlo;
    size_t aoff = (size_t)(row0 + ar) * 128 + (kc & 3) * 32 + af * 8;
    uint4 a_h = *(const uint4*)(Phi + aoff);
    uint4 a_l = *(const uint4*)(Plo + aoff);
    size_t woff = (size_t)bc * 256 + kc * 32 + bs;
    uint4 b_h0 = *(const uint4*)(WThi + woff);
    uint4 b_h1 = *(const uint4*)(WThi + woff + 8);
    uint4 b_l0 = *(const uint4*)(WTlo + woff);
    uint4 b_l1 = *(const uint4*)(WTlo + woff + 8);
    __syncthreads();
    *(uint4*)&Ah[ar][af * 8] = a_h;
    *(uint4*)&Al[ar][af * 8] = a_l;
    *(uint4*)&Bh[bc][bs] = b_h0;
    *(uint4*)&Bh[bc][bs + 8] = b_h1;
    *(uint4*)&Bl[bc][bs] = b_l0;
    *(uint4*)&Bl[bc][bs + 8] = b_l1;
    __syncthreads();
    short8v ah[2], al2[2], bfh[4], bfl[4];
#pragma unroll
    for (int rf = 0; rf < 2; ++rf) {
      ah[rf]  = *(const short8v*)&Ah[wr + rf * 16 + li][lg * 8];
      al2[rf] = *(const short8v*)&Al[wr + rf * 16 + li][lg * 8];
    }
#pragma unroll
    for (int cf = 0; cf < 4; ++cf) {
      bfh[cf] = *(const short8v*)&Bh[wc + cf * 16 + li][lg * 8];
      bfl[cf] = *(const short8v*)&Bl[wc + cf * 16 + li][lg * 8];
    }
#pragma unroll
    for (int rf = 0; rf < 2; ++rf)
#pragma unroll
      for (int cf = 0; cf < 4; ++cf) {
        acc[rf][cf] = __builtin_amdgcn_mfma_f32_16x16x32_bf16(ah[rf], bfh[cf], acc[rf][cf], 0, 0, 0);
        acc[rf][cf] = __builtin_amdgcn_mfma_f32_16x16x32_bf16(al2[rf], bfh[cf], acc[rf][cf], 0, 0, 0);
        acc[rf][cf] = __builtin_amdgcn_mfma_f32_16x16x32_bf16(ah[rf], bfl[cf], acc[rf][cf], 0, 0, 0);
      }
  }

  // epilogue: C/D layout col=lane&15, row=(lane>>4)*4+reg
#pragma unroll
  for (int rf = 0; rf < 2; ++rf) {
#pragma unroll
    for (int cf = 0; cf < 4; ++cf) {
      int c = wc + cf * 16 + li;
      float bv = bias[c];
#pragma unroll
      for (int reg = 0; reg < 4; ++reg) {
        int r = row0 + wr + rf * 16 + lg * 4 + reg;
        float v = acc[rf][cf][reg] + bv;
        v = v > 0.f ? v : 0.f;
        unsigned short h = f2b(v);
        Ohi[(size_t)r * 128 + c] = h;
        Olo[(size_t)r * 128 + c] = f2b(v - b2f(h));
      }
    }
  }
}

// ---------------- layer-4 projection from hi/lo planes ----------------

__global__ __launch_bounds__(256) void k_lastproj(const unsigned short* __restrict__ Hhi,
                                                  const unsigned short* __restrict__ Hlo,
                                                  const float* __restrict__ Wl,
                                                  const float* __restrict__ Wr,
                                                  const float* __restrict__ bias,
                                                  float* __restrict__ U,
                                                  float* __restrict__ V) {
  __shared__ float As[64][132];
  const int t = threadIdx.x;
  const int row0 = blockIdx.x * 64;

#pragma unroll
  for (int i = 0; i < 8; ++i) {
    int idx = i * 256 + t;
    int r = idx >> 5, c4 = idx & 31;
    size_t off = (size_t)(row0 + r) * 128 + c4 * 4;
    ushort4 h = *(const ushort4*)(Hhi + off);
    ushort4 l = *(const ushort4*)(Hlo + off);
    float4 v;
    v.x = b2f(h.x) + b2f(l.x);
    v.y = b2f(h.y) + b2f(l.y);
    v.z = b2f(h.z) + b2f(l.z);
    v.w = b2f(h.w) + b2f(l.w);
    *(float4*)&As[r][c4 * 4] = v;
  }
  __syncthreads();

  const int r = t & 63;
  const int g = t >> 6;
  const bool isV = g >= 2;
  const int st = (g & 1) ? 9 : 0;
  const int cnt = (g & 1) ? 8 : 9;
  const float* __restrict__ W = isV ? Wr : Wl;

  float acc[9];
#pragma unroll
  for (int j = 0; j < 9; ++j) {
    int jj = st + j; if (jj > 16) jj = 16;
    acc[j] = isV ? bias[jj] : 0.f;
  }

#pragma unroll 4
  for (int k4 = 0; k4 < 32; ++k4) {
    float4 a = *(const float4*)&As[r][k4 * 4];
    const float* w0 = W + (size_t)(k4 * 4) * DO + st;
#pragma unroll
    for (int j = 0; j < 9; ++j) {
      int jc = (st + j > 16) ? (16 - st) : j;
      acc[j] = fmaf(a.x, w0[jc], acc[j]);
      acc[j] = fmaf(a.y, w0[DO + jc], acc[j]);
      acc[j] = fmaf(a.z, w0[2 * DO + jc], acc[j]);
      acc[j] = fmaf(a.w, w0[3 * DO + jc], acc[j]);
    }
  }

  float* __restrict__ dstbuf = isV ? V : U;
  const size_t base = (size_t)(row0 + r) * DO + st;
#pragma unroll
  for (int j = 0; j < 9; ++j)
    if (j < cnt) dstbuf[base + j] = acc[j];
}

// ---------------- 17-dim aggregation + epilogue (layer 4) ----------------

__global__ __launch_bounds__(256) void k_agg17(const float* __restrict__ U,
                                               const float* __restrict__ V,
                                               const int* __restrict__ cursor,
                                               const unsigned short* __restrict__ csr,
                                               float* __restrict__ out) {
  int t = blockIdx.x * 256 + threadIdx.x;
  int node = t / DO;
  if (node >= NN) return;
  int ch = t - node * DO;
  int deg = cursor[node];
  int cnt = deg > SLOTS ? SLOTS : deg;
  const unsigned short* idx = csr + ((size_t)node << 6);
  float acc = 0.f;
#define GATH(S, COND) if (COND) acc += U[(size_t)(S)*DO + ch];
  for (int base = 0; base < cnt; base += 8) {
    ushort4 i0 = *(const ushort4*)(idx + base);
    ushort4 i1 = *(const ushort4*)(idx + base + 4);
    GATH(i0.x, true)
    GATH(i0.y, base + 1 < cnt)
    GATH(i0.z, base + 2 < cnt)
    GATH(i0.w, base + 3 < cnt)
    GATH(i1.x, base + 4 < cnt)
    GATH(i1.y, base + 5 < cnt)
    GATH(i1.z, base + 6 < cnt)
    GATH(i1.w, base + 7 < cnt)
  }
#undef GATH
  float inv = 1.0f / (float)(deg > 0 ? deg : 1);
  out[(size_t)node * DO + ch] = fmaxf(fmaf(acc, inv, V[(size_t)node * DO + ch]), 0.f);
}

// ---------------- launch ----------------

extern "C" void kernel_launch(void* const* d_in, const int* in_sizes, int n_in,
                              void* d_out, int out_size, void* d_ws, size_t ws_size,
                              hipStream_t stream) {
  const float* x = (const float*)d_in[0];
  const int* ei = (const int*)d_in[1];  // [2][NE] int32
  const int* src = ei;
  const int* dst = ei + NE;
  const float *wl[5], *bl[5], *wr[5];
  for (int i = 0; i < 5; ++i) {
    wl[i] = (const float*)d_in[2 + 3 * i];
    bl[i] = (const float*)d_in[3 + 3 * i];
    wr[i] = (const float*)d_in[4 + 3 * i];
  }

  char* ws = (char*)d_ws;
  int* cursor = (int*)ws;                      ws += 160256;
  unsigned short* csr = (unsigned short*)ws;   ws += (size_t)NN * SLOTS * 2;  // 5.12 MB
  unsigned short* Hhi = (unsigned short*)ws;   ws += (size_t)NN * DH * 2;     // 10.24 MB
  unsigned short* Hlo = (unsigned short*)ws;   ws += (size_t)NN * DH * 2;
  unsigned short* Mhi = (unsigned short*)ws;   ws += (size_t)NN * DH * 2;
  unsigned short* Mlo = (unsigned short*)ws;   ws += (size_t)NN * DH * 2;
  unsigned short* WThi = (unsigned short*)ws;  ws += (size_t)4 * 128 * 256 * 2;  // 256 KB
  unsigned short* WTlo = (unsigned short*)ws;  ws += (size_t)4 * 128 * 256 * 2;
  float* U = (float*)Mhi;   // M planes dead by layer 4
  float* V = U + (size_t)NN * DO;

  hipMemsetAsync(cursor, 0, NN * sizeof(int), stream);
  k_prep<<<8012, 256, 0, stream>>>(src, dst, x,
                                   wl[0], wr[0], wl[1], wr[1],
                                   wl[2], wr[2], wl[3], wr[3],
                                   cursor, csr, Hhi, Hlo, WThi, WTlo);

  const int AGG_GRID = (NN * 32 + 255) / 256;  // 5000
  const int GEMM_GRID = NN / 64;               // 625

  for (int l = 0; l < 4; ++l) {
    k_agg<<<AGG_GRID, 256, 0, stream>>>(Hhi, Mhi, Mlo, cursor, csr);
    k_gemm_mfma<<<GEMM_GRID, 256, 0, stream>>>(Mhi, Mlo, Hhi, Hlo,
                                               WThi + (size_t)l * 32768,
                                               WTlo + (size_t)l * 32768,
                                               bl[l], Hhi, Hlo);
  }
  // L4
  k_lastproj<<<NN / 64, 256, 0, stream>>>(Hhi, Hlo, wl[4], wr[4], bl[4], U, V);
  k_agg17<<<(NN * DO + 255) / 256, 256, 0, stream>>>(U, V, cursor, csr,
                                                     (float*)d_out);
}

// Round 15
// 353.720 us; speedup vs baseline: 1.5046x; 1.0394x over previous
//
#include <hip/hip_runtime.h>

#define NN 40000
#define NE 640000
#define DH 128
#define DO 17
#define SLOTS 64

typedef __attribute__((ext_vector_type(8))) short short8v;
typedef __attribute__((ext_vector_type(4))) float f32x4;

__device__ inline float b2f(unsigned short u) {
  union { unsigned int i; float f; } c;
  c.i = (unsigned int)u << 16;
  return c.f;
}
__device__ inline unsigned short f2b(float f) {
  union { float f; unsigned int i; } c;
  c.f = f;
  unsigned int r = c.i + 0x7fff + ((c.i >> 16) & 1);  // RNE
  return (unsigned short)(r >> 16);
}

// ---------------- fused prep: CSR fill + x->bf16 + weight split ----------------
// Grid-partitioned: [0,2500) edge fill, [2500,7500) tobf16, [7500,8012) splitw.

__global__ __launch_bounds__(256) void k_prep(
    const int* __restrict__ src, const int* __restrict__ dst,
    const float* __restrict__ x,
    const float* __restrict__ Wl0, const float* __restrict__ Wr0,
    const float* __restrict__ Wl1, const float* __restrict__ Wr1,
    const float* __restrict__ Wl2, const float* __restrict__ Wr2,
    const float* __restrict__ Wl3, const float* __restrict__ Wr3,
    int* __restrict__ cursor, unsigned short* __restrict__ csr,
    unsigned short* __restrict__ Hhi,
    unsigned short* __restrict__ WThi, unsigned short* __restrict__ WTlo) {
  const int bid = blockIdx.x;
  const int tid = threadIdx.x;
  if (bid < 2500) {                       // ---- CSR fill ----
    int e = bid * 256 + tid;
    if (e < NE) {
      int d = dst[e];
      int pos = atomicAdd(&cursor[d], 1);
      if (pos < SLOTS) csr[(d << 6) + pos] = (unsigned short)src[e];
    }
  } else if (bid < 7500) {                // ---- x -> bf16 ----
    int t = (bid - 2500) * 256 + tid;
    if (t < NN * 32) {
      float4 v = *(const float4*)(x + (size_t)t * 4);
      ushort4 h;
      h.x = f2b(v.x); h.y = f2b(v.y); h.z = f2b(v.z); h.w = f2b(v.w);
      *(ushort4*)(Hhi + (size_t)t * 4) = h;
    }
  } else {                                // ---- weight transpose + split ----
    int q = bid - 7500;                   // 0..511
    int l = q >> 7;
    int n = q & 127;
    const float* Wl = (l == 0) ? Wl0 : (l == 1) ? Wl1 : (l == 2) ? Wl2 : Wl3;
    const float* Wr = (l == 0) ? Wr0 : (l == 1) ? Wr1 : (l == 2) ? Wr2 : Wr3;
    int k = tid;
    float v = (k < 128) ? Wl[(size_t)k * 128 + n] : Wr[(size_t)(k - 128) * 128 + n];
    unsigned short hi = f2b(v);
    unsigned short lo = f2b(v - b2f(hi));
    size_t base = (size_t)l * 32768 + (size_t)n * 256 + k;
    WThi[base] = hi;
    WTlo[base] = lo;
  }
}

// ---------------- mean aggregation: bf16 rows, 16-deep MLP ----------------
// Output written as hi/lo split planes (mean keeps near-fp32 precision).

__global__ __launch_bounds__(256) void k_agg(const unsigned short* __restrict__ in,
                                             unsigned short* __restrict__ Mhi,
                                             unsigned short* __restrict__ Mlo,
                                             const int* __restrict__ cursor,
                                             const unsigned short* __restrict__ csr) {
  int t = blockIdx.x * 256 + threadIdx.x;
  int node = t >> 5;
  if (node >= NN) return;
  int ch = threadIdx.x & 31;
  int deg = cursor[node];
  int cnt = deg > SLOTS ? SLOTS : deg;
  const ushort4* in4 = (const ushort4*)in;
  const unsigned short* idx = csr + ((size_t)node << 6);
  float ax = 0.f, ay = 0.f, az = 0.f, aw = 0.f;

  if (cnt > 0) {
    const int s0 = idx[0];
    for (int b = 0; b < cnt; b += 16) {
      ushort4 i0 = *(const ushort4*)(idx + b);
      ushort4 i1 = *(const ushort4*)(idx + b + 4);
      ushort4 i2 = *(const ushort4*)(idx + b + 8);
      ushort4 i3 = *(const ushort4*)(idx + b + 12);
      int s[16];
      s[0]  = i0.x;
      s[1]  = (b + 1  < cnt) ? i0.y : s0;
      s[2]  = (b + 2  < cnt) ? i0.z : s0;
      s[3]  = (b + 3  < cnt) ? i0.w : s0;
      s[4]  = (b + 4  < cnt) ? i1.x : s0;
      s[5]  = (b + 5  < cnt) ? i1.y : s0;
      s[6]  = (b + 6  < cnt) ? i1.z : s0;
      s[7]  = (b + 7  < cnt) ? i1.w : s0;
      s[8]  = (b + 8  < cnt) ? i2.x : s0;
      s[9]  = (b + 9  < cnt) ? i2.y : s0;
      s[10] = (b + 10 < cnt) ? i2.z : s0;
      s[11] = (b + 11 < cnt) ? i2.w : s0;
      s[12] = (b + 12 < cnt) ? i3.x : s0;
      s[13] = (b + 13 < cnt) ? i3.y : s0;
      s[14] = (b + 14 < cnt) ? i3.z : s0;
      s[15] = (b + 15 < cnt) ? i3.w : s0;
      ushort4 v[16];
#pragma unroll
      for (int k = 0; k < 16; ++k) v[k] = in4[(size_t)s[k] * 32 + ch];
#pragma unroll
      for (int k = 0; k < 16; ++k) {
        if (b + k < cnt) {
          ax += b2f(v[k].x); ay += b2f(v[k].y);
          az += b2f(v[k].z); aw += b2f(v[k].w);
        }
      }
    }
  }
  float inv = 1.0f / (float)(deg > 0 ? deg : 1);
  ax *= inv; ay *= inv; az *= inv; aw *= inv;
  ushort4 h, l;
  h.x = f2b(ax); l.x = f2b(ax - b2f(h.x));
  h.y = f2b(ay); l.y = f2b(ay - b2f(h.y));
  h.z = f2b(az); l.z = f2b(az - b2f(h.z));
  h.w = f2b(aw); l.w = f2b(aw - b2f(h.w));
  *(ushort4*)(Mhi + (size_t)node * 128 + ch * 4) = h;
  *(ushort4*)(Mlo + (size_t)node * 128 + ch * 4) = l;
}

// ---------------- MFMA GEMM v3: h' = relu([M|h] @ WT^T + b) ----------------
// BM=64, BN=128, 4 waves 2x2. Mean side split (3 MFMA), h side bf16-only
// (2 MFMA). h stored/written as single bf16 plane. In-place update.

__global__ __launch_bounds__(256) void k_gemm_mfma(
    const unsigned short* __restrict__ Mhi,
    const unsigned short* __restrict__ Mlo,
    const unsigned short* Hhi,              // no restrict: aliases Ohi
    const unsigned short* __restrict__ WThi,
    const unsigned short* __restrict__ WTlo,
    const float* __restrict__ bias,
    unsigned short* Ohi) {
  __shared__ unsigned short Ah[64][40];
  __shared__ unsigned short Al[64][40];
  __shared__ unsigned short Bh[128][40];
  __shared__ unsigned short Bl[128][40];
  const int tid = threadIdx.x;
  const int row0 = blockIdx.x * 64;
  const int w = tid >> 6;
  const int lane = tid & 63;
  const int li = lane & 15;
  const int lg = lane >> 4;
  const int wr = (w & 1) * 32;
  const int wc = (w >> 1) * 64;

  f32x4 acc[2][4];
#pragma unroll
  for (int i = 0; i < 2; ++i)
#pragma unroll
    for (int j = 0; j < 4; ++j) acc[i][j] = (f32x4){0.f, 0.f, 0.f, 0.f};

  const int ar = tid >> 2, af = tid & 3;
  const int bc = tid >> 1, bs = (tid & 1) * 16;

  for (int kc = 0; kc < 8; ++kc) {
    const bool mside = (kc < 4);
    size_t aoff = (size_t)(row0 + ar) * 128 + (kc & 3) * 32 + af * 8;
    uint4 a_h = *(const uint4*)((mside ? Mhi : Hhi) + aoff);
    uint4 a_l;
    if (mside) a_l = *(const uint4*)(Mlo + aoff);
    size_t woff = (size_t)bc * 256 + kc * 32 + bs;
    uint4 b_h0 = *(const uint4*)(WThi + woff);
    uint4 b_h1 = *(const uint4*)(WThi + woff + 8);
    uint4 b_l0 = *(const uint4*)(WTlo + woff);
    uint4 b_l1 = *(const uint4*)(WTlo + woff + 8);
    __syncthreads();
    *(uint4*)&Ah[ar][af * 8] = a_h;
    if (mside) *(uint4*)&Al[ar][af * 8] = a_l;
    *(uint4*)&Bh[bc][bs] = b_h0;
    *(uint4*)&Bh[bc][bs + 8] = b_h1;
    *(uint4*)&Bl[bc][bs] = b_l0;
    *(uint4*)&Bl[bc][bs + 8] = b_l1;
    __syncthreads();
    short8v ah[2], al2[2], bfh[4], bfl[4];
#pragma unroll
    for (int rf = 0; rf < 2; ++rf) {
      ah[rf] = *(const short8v*)&Ah[wr + rf * 16 + li][lg * 8];
      if (mside) al2[rf] = *(const short8v*)&Al[wr + rf * 16 + li][lg * 8];
    }
#pragma unroll
    for (int cf = 0; cf < 4; ++cf) {
      bfh[cf] = *(const short8v*)&Bh[wc + cf * 16 + li][lg * 8];
      bfl[cf] = *(const short8v*)&Bl[wc + cf * 16 + li][lg * 8];
    }
    if (mside) {
#pragma unroll
      for (int rf = 0; rf < 2; ++rf)
#pragma unroll
        for (int cf = 0; cf < 4; ++cf) {
          acc[rf][cf] = __builtin_amdgcn_mfma_f32_16x16x32_bf16(ah[rf], bfh[cf], acc[rf][cf], 0, 0, 0);
          acc[rf][cf] = __builtin_amdgcn_mfma_f32_16x16x32_bf16(al2[rf], bfh[cf], acc[rf][cf], 0, 0, 0);
          acc[rf][cf] = __builtin_amdgcn_mfma_f32_16x16x32_bf16(ah[rf], bfl[cf], acc[rf][cf], 0, 0, 0);
        }
    } else {
#pragma unroll
      for (int rf = 0; rf < 2; ++rf)
#pragma unroll
        for (int cf = 0; cf < 4; ++cf) {
          acc[rf][cf] = __builtin_amdgcn_mfma_f32_16x16x32_bf16(ah[rf], bfh[cf], acc[rf][cf], 0, 0, 0);
          acc[rf][cf] = __builtin_amdgcn_mfma_f32_16x16x32_bf16(ah[rf], bfl[cf], acc[rf][cf], 0, 0, 0);
        }
    }
  }

  // epilogue: C/D layout col=lane&15, row=(lane>>4)*4+reg
#pragma unroll
  for (int rf = 0; rf < 2; ++rf) {
#pragma unroll
    for (int cf = 0; cf < 4; ++cf) {
      int c = wc + cf * 16 + li;
      float bv = bias[c];
#pragma unroll
      for (int reg = 0; reg < 4; ++reg) {
        int r = row0 + wr + rf * 16 + lg * 4 + reg;
        float v = acc[rf][cf][reg] + bv;
        v = v > 0.f ? v : 0.f;
        Ohi[(size_t)r * 128 + c] = f2b(v);
      }
    }
  }
}

// ---------------- layer-4 projection from bf16 h ----------------

__global__ __launch_bounds__(256) void k_lastproj(const unsigned short* __restrict__ Hhi,
                                                  const float* __restrict__ Wl,
                                                  const float* __restrict__ Wr,
                                                  const float* __restrict__ bias,
                                                  float* __restrict__ U,
                                                  float* __restrict__ V) {
  __shared__ float As[64][132];
  const int t = threadIdx.x;
  const int row0 = blockIdx.x * 64;

#pragma unroll
  for (int i = 0; i < 8; ++i) {
    int idx = i * 256 + t;
    int r = idx >> 5, c4 = idx & 31;
    size_t off = (size_t)(row0 + r) * 128 + c4 * 4;
    ushort4 h = *(const ushort4*)(Hhi + off);
    float4 v;
    v.x = b2f(h.x); v.y = b2f(h.y); v.z = b2f(h.z); v.w = b2f(h.w);
    *(float4*)&As[r][c4 * 4] = v;
  }
  __syncthreads();

  const int r = t & 63;
  const int g = t >> 6;
  const bool isV = g >= 2;
  const int st = (g & 1) ? 9 : 0;
  const int cnt = (g & 1) ? 8 : 9;
  const float* __restrict__ W = isV ? Wr : Wl;

  float acc[9];
#pragma unroll
  for (int j = 0; j < 9; ++j) {
    int jj = st + j; if (jj > 16) jj = 16;
    acc[j] = isV ? bias[jj] : 0.f;
  }

#pragma unroll 4
  for (int k4 = 0; k4 < 32; ++k4) {
    float4 a = *(const float4*)&As[r][k4 * 4];
    const float* w0 = W + (size_t)(k4 * 4) * DO + st;
#pragma unroll
    for (int j = 0; j < 9; ++j) {
      int jc = (st + j > 16) ? (16 - st) : j;
      acc[j] = fmaf(a.x, w0[jc], acc[j]);
      acc[j] = fmaf(a.y, w0[DO + jc], acc[j]);
      acc[j] = fmaf(a.z, w0[2 * DO + jc], acc[j]);
      acc[j] = fmaf(a.w, w0[3 * DO + jc], acc[j]);
    }
  }

  float* __restrict__ dstbuf = isV ? V : U;
  const size_t base = (size_t)(row0 + r) * DO + st;
#pragma unroll
  for (int j = 0; j < 9; ++j)
    if (j < cnt) dstbuf[base + j] = acc[j];
}

// ---------------- 17-dim aggregation + epilogue (layer 4) ----------------

__global__ __launch_bounds__(256) void k_agg17(const float* __restrict__ U,
                                               const float* __restrict__ V,
                                               const int* __restrict__ cursor,
                                               const unsigned short* __restrict__ csr,
                                               float* __restrict__ out) {
  int t = blockIdx.x * 256 + threadIdx.x;
  int node = t / DO;
  if (node >= NN) return;
  int ch = t - node * DO;
  int deg = cursor[node];
  int cnt = deg > SLOTS ? SLOTS : deg;
  const unsigned short* idx = csr + ((size_t)node << 6);
  float acc = 0.f;
#define GATH(S, COND) if (COND) acc += U[(size_t)(S)*DO + ch];
  for (int base = 0; base < cnt; base += 8) {
    ushort4 i0 = *(const ushort4*)(idx + base);
    ushort4 i1 = *(const ushort4*)(idx + base + 4);
    GATH(i0.x, true)
    GATH(i0.y, base + 1 < cnt)
    GATH(i0.z, base + 2 < cnt)
    GATH(i0.w, base + 3 < cnt)
    GATH(i1.x, base + 4 < cnt)
    GATH(i1.y, base + 5 < cnt)
    GATH(i1.z, base + 6 < cnt)
    GATH(i1.w, base + 7 < cnt)
  }
#undef GATH
  float inv = 1.0f / (float)(deg > 0 ? deg : 1);
  out[(size_t)node * DO + ch] = fmaxf(fmaf(acc, inv, V[(size_t)node * DO + ch]), 0.f);
}

// ---------------- launch ----------------

extern "C" void kernel_launch(void* const* d_in, const int* in_sizes, int n_in,
                              void* d_out, int out_size, void* d_ws, size_t ws_size,
                              hipStream_t stream) {
  const float* x = (const float*)d_in[0];
  const int* ei = (const int*)d_in[1];  // [2][NE] int32
  const int* src = ei;
  const int* dst = ei + NE;
  const float *wl[5], *bl[5], *wr[5];
  for (int i = 0; i < 5; ++i) {
    wl[i] = (const float*)d_in[2 + 3 * i];
    bl[i] = (const float*)d_in[3 + 3 * i];
    wr[i] = (const float*)d_in[4 + 3 * i];
  }

  char* ws = (char*)d_ws;
  int* cursor = (int*)ws;                      ws += 160256;
  unsigned short* csr = (unsigned short*)ws;   ws += (size_t)NN * SLOTS * 2;  // 5.12 MB
  unsigned short* Hhi = (unsigned short*)ws;   ws += (size_t)NN * DH * 2;     // 10.24 MB
  unsigned short* Mhi = (unsigned short*)ws;   ws += (size_t)NN * DH * 2;
  unsigned short* Mlo = (unsigned short*)ws;   ws += (size_t)NN * DH * 2;
  unsigned short* WThi = (unsigned short*)ws;  ws += (size_t)4 * 128 * 256 * 2;  // 256 KB
  unsigned short* WTlo = (unsigned short*)ws;  ws += (size_t)4 * 128 * 256 * 2;
  float* U = (float*)Mhi;   // M planes dead by layer 4
  float* V = U + (size_t)NN * DO;

  hipMemsetAsync(cursor, 0, NN * sizeof(int), stream);
  k_prep<<<8012, 256, 0, stream>>>(src, dst, x,
                                   wl[0], wr[0], wl[1], wr[1],
                                   wl[2], wr[2], wl[3], wr[3],
                                   cursor, csr, Hhi, WThi, WTlo);

  const int AGG_GRID = (NN * 32 + 255) / 256;  // 5000
  const int GEMM_GRID = NN / 64;               // 625

  for (int l = 0; l < 4; ++l) {
    k_agg<<<AGG_GRID, 256, 0, stream>>>(Hhi, Mhi, Mlo, cursor, csr);
    k_gemm_mfma<<<GEMM_GRID, 256, 0, stream>>>(Mhi, Mlo, Hhi,
                                               WThi + (size_t)l * 32768,
                                               WTlo + (size_t)l * 32768,
                                               bl[l], Hhi);
  }
  // L4
  k_lastproj<<<NN / 64, 256, 0, stream>>>(Hhi, wl[4], wr[4], bl[4], U, V);
  k_agg17<<<(NN * DO + 255) / 256, 256, 0, stream>>>(U, V, cursor, csr,
                                                     (float*)d_out);
}